// Round 9
// baseline (318.760 us; speedup 1.0000x reference)
//
#include <hip/hip_runtime.h>

typedef unsigned short ushort_t;
typedef __attribute__((ext_vector_type(8))) short bf16x8;     // 8 bf16 (4 VGPRs)
typedef __attribute__((ext_vector_type(4))) float f32x4;
typedef __attribute__((ext_vector_type(4))) unsigned short us4;

#define DM 2048
#define RK 64

__device__ __forceinline__ ushort_t f2b(float f) {
    union { float f; unsigned u; } x; x.f = f;
    unsigned r = x.u + 0x7fff + ((x.u >> 16) & 1);   // RNE
    return (ushort_t)(r >> 16);
}

// ---------------- P1: Mmid[64][64] = butterfly(Wbs) @ Wcr ----------------
__global__ void k_p1(const float* __restrict__ Wbs, const float* __restrict__ Af,
                     const float* __restrict__ Wcr, float* __restrict__ Mmid) {
    __shared__ float X[64 * 256];          // 64 KB, becomes T1
    const int tid = threadIdx.x;
#pragma unroll
    for (int i = 0; i < 16; ++i) {
        int e = (i * 256 + tid) * 4;
        *(float4*)&X[e] = *(const float4*)&Wbs[e];
    }
    __syncthreads();
#pragma unroll
    for (int l = 0; l < 8; ++l) {
        const int bit = 1 << (7 - l);
        const float a00 = Af[l * 4 + 0], a01 = Af[l * 4 + 1];
        const float a10 = Af[l * 4 + 2], a11 = Af[l * 4 + 3];
#pragma unroll 4
        for (int p = 0; p < 32; ++p) {
            int pid = p * 256 + tid;
            int row = pid >> 7;
            int off = pid & 127;
            int lo = off & (bit - 1);
            int n0 = ((off ^ lo) << 1) | lo;
            int n1 = n0 | bit;
            float x0 = X[row * 256 + n0], x1 = X[row * 256 + n1];
            X[row * 256 + n0] = x0 * a00 + x1 * a10;
            X[row * 256 + n1] = x0 * a01 + x1 * a11;
        }
        __syncthreads();
    }
    int g = blockIdx.x * 256 + tid;
    int r1 = g >> 6, r2 = g & 63;
    float s = 0.f;
#pragma unroll 8
    for (int n = 0; n < 256; ++n) s += X[r1 * 256 + n] * Wcr[n * 64 + r2];
    Mmid[g] = s;
}

// ---------------- P2: WeffT[64][2048] = (Wbr @ Mmid)^T, WcT[2048][64] = Wcm^T ----
__global__ void k_p2(const float* __restrict__ Wbr, const float* __restrict__ Mmid,
                     const float* __restrict__ Wcm,
                     ushort_t* __restrict__ WeffT, ushort_t* __restrict__ WcT) {
    const int b = blockIdx.x, tid = threadIdx.x;
    if (b < 32) {
        __shared__ float LW[64][65];
        __shared__ float LM[64 * 64];
#pragma unroll
        for (int i = 0; i < 4; ++i) {
            int e = (i * 256 + tid) * 4;
            int kk = e >> 6, r = e & 63;
            float4 v = *(const float4*)&Wbr[(size_t)b * 4096 + e];
            LW[kk][r] = v.x; LW[kk][r + 1] = v.y; LW[kk][r + 2] = v.z; LW[kk][r + 3] = v.w;
        }
#pragma unroll
        for (int i = 0; i < 4; ++i) {
            int e = (i * 256 + tid) * 4;
            *(float4*)&LM[e] = *(const float4*)&Mmid[e];
        }
        __syncthreads();
        int kk = tid & 63, n0 = (tid >> 6) * 16;
        float acc[16];
#pragma unroll
        for (int j = 0; j < 16; ++j) acc[j] = 0.f;
        for (int r = 0; r < 64; ++r) {
            float wv = LW[kk][r];
            const float* mrow = &LM[r * 64 + n0];
            float4 m0 = *(const float4*)(mrow);
            float4 m1 = *(const float4*)(mrow + 4);
            float4 m2 = *(const float4*)(mrow + 8);
            float4 m3 = *(const float4*)(mrow + 12);
            acc[0] += wv * m0.x; acc[1] += wv * m0.y; acc[2] += wv * m0.z; acc[3] += wv * m0.w;
            acc[4] += wv * m1.x; acc[5] += wv * m1.y; acc[6] += wv * m1.z; acc[7] += wv * m1.w;
            acc[8] += wv * m2.x; acc[9] += wv * m2.y; acc[10] += wv * m2.z; acc[11] += wv * m2.w;
            acc[12] += wv * m3.x; acc[13] += wv * m3.y; acc[14] += wv * m3.z; acc[15] += wv * m3.w;
        }
#pragma unroll
        for (int j = 0; j < 16; ++j)
            WeffT[(size_t)(n0 + j) * DM + b * 64 + kk] = f2b(acc[j]);
    } else {
        __shared__ float LT[64][65];
        const int n0 = (b - 32) * 64;
#pragma unroll
        for (int i = 0; i < 4; ++i) {
            int e = (i * 256 + tid) * 4;
            int k = e >> 6, nn = e & 63;
            float4 v = *(const float4*)&Wcm[(size_t)k * DM + n0 + nn];
            LT[k][nn] = v.x; LT[k][nn + 1] = v.y; LT[k][nn + 2] = v.z; LT[k][nn + 3] = v.w;
        }
        __syncthreads();
#pragma unroll
        for (int i = 0; i < 4; ++i) {
            int e = (i * 256 + tid) * 4;
            int nn = e >> 6, k = e & 63;
            us4 o;
            o.x = f2b(LT[k][nn]); o.y = f2b(LT[k + 1][nn]);
            o.z = f2b(LT[k + 2][nn]); o.w = f2b(LT[k + 3][nn]);
            *(us4*)&WcT[(size_t)(n0 + nn) * RK + k] = o;
        }
    }
}

// ---------------- fused main: out = (u @ W_eff) @ W_c_model + D*u ----------------
// 256 blocks x 8 waves x 64 rows, PER-GROUP phase fusion:
//   for each 16-row group: phase1 (u HBM -> MFMA w/ register-pinned Wf) ->
//   cross-wave reduce -> phase2 (t @ WcT + D*u, u re-read is L2-hot, NT store).
// Wf pinned via asm "+v": compiler cannot re-materialize -> true residency
// (R8 compiled to 96 VGPR => weights were re-loaded from L2 every group).
// tsh double-buffered by group parity -> 2 barriers per group.
__global__ __launch_bounds__(512) void k_main(const float* __restrict__ u,
                                              const ushort_t* __restrict__ WeffT,
                                              const ushort_t* __restrict__ WcT,
                                              const float* __restrict__ Dvec,
                                              float* __restrict__ out) {
    __shared__ float red[8][64][20];       // 40 KB partial-t, [wave][n][r]
    __shared__ ushort_t tsh[2][16 * 72];   // 4.5 KB t bf16, dbuf by group parity

    const int tid = threadIdx.x;
    const int w = tid >> 6;                // wave 0..7 -> K-slice [w*256,+256)
    const int lane = tid & 63;
    const int m16 = lane & 15;
    const int quad = lane >> 4;
    const size_t r0 = (size_t)blockIdx.x * 64;

    // ---- preload stationary weight fragments (32 x 16B, L2-resident) ----
    bf16x8 Wf[8][4];
    {
        const ushort_t* wbase = WeffT + (size_t)m16 * DM + w * 256 + quad * 8;
#pragma unroll
        for (int c = 0; c < 8; ++c)
#pragma unroll
            for (int j = 0; j < 4; ++j)
                Wf[c][j] = *(const bf16x8*)(wbase + (size_t)j * 16 * DM + c * 32);
    }
    // pin: mark each fragment as modified -> compiler must keep it in VGPRs
#pragma unroll
    for (int c = 0; c < 8; ++c)
#pragma unroll
        for (int j = 0; j < 4; ++j)
            asm volatile("" : "+v"(Wf[c][j]));

    const int cb = w * 256;                // phase-2 col-slice of this wave

    for (int g = 0; g < 4; ++g) {
        // ---- phase 1: t-partial for rows [g*16, +16), K-slice [w*256,+256) ----
        const float* ap = u + (r0 + g * 16 + m16) * DM + w * 256 + quad * 8;
        f32x4 acc[4];
#pragma unroll
        for (int j = 0; j < 4; ++j) acc[j] = (f32x4){0.f, 0.f, 0.f, 0.f};

#pragma unroll
        for (int c = 0; c < 8; ++c) {
            float4 u0 = *(const float4*)(ap + c * 32);
            float4 u1 = *(const float4*)(ap + c * 32 + 4);
            bf16x8 a;
            a[0] = (short)f2b(u0.x); a[1] = (short)f2b(u0.y);
            a[2] = (short)f2b(u0.z); a[3] = (short)f2b(u0.w);
            a[4] = (short)f2b(u1.x); a[5] = (short)f2b(u1.y);
            a[6] = (short)f2b(u1.z); a[7] = (short)f2b(u1.w);
#pragma unroll
            for (int j = 0; j < 4; ++j)
                acc[j] = __builtin_amdgcn_mfma_f32_16x16x32_bf16(a, Wf[c][j], acc[j], 0, 0, 0);
        }

        // partial t: acc[j][i] = t[r = quad*4+i][n = 16j+m16]
#pragma unroll
        for (int j = 0; j < 4; ++j)
            *(f32x4*)&red[w][16 * j + m16][quad * 4] = acc[j];
        __syncthreads();

        // ---- reduce (R2 mapping: float2 over contiguous r) -> tsh[g&1] ----
        {
            const int n = tid >> 3;             // 0..63
            const int r2 = (tid & 7) * 2;       // 0..14 even
            float s0 = 0.f, s1 = 0.f;
#pragma unroll
            for (int ww = 0; ww < 8; ++ww) {
                float2 v = *(const float2*)&red[ww][n][r2];
                s0 += v.x; s1 += v.y;
            }
            tsh[g & 1][r2 * 72 + n]       = f2b(s0);
            tsh[g & 1][(r2 + 1) * 72 + n] = f2b(s1);
        }
        __syncthreads();

        // ---- phase 2: rows [g*16,+16) x cols [cb,+256); u re-read L2-hot ----
        const ushort_t* tb = tsh[g & 1];
        bf16x8 ta0 = *(const bf16x8*)&tb[m16 * 72 + quad * 8];
        bf16x8 ta1 = *(const bf16x8*)&tb[m16 * 72 + 32 + quad * 8];
        const ushort_t* wcb = WcT + (size_t)(cb + m16) * RK + quad * 8;
        const float* up = u + (r0 + g * 16 + m16) * DM + cb + quad * 4;
        const float* dp = Dvec + cb + quad * 4;
        float* op = out + (r0 + g * 16 + m16) * DM + cb + quad * 4;
#pragma unroll 4
        for (int ct = 0; ct < 16; ++ct) {
            const ushort_t* p = wcb + (size_t)ct * 16 * RK;
            bf16x8 wb0 = *(const bf16x8*)(p);
            bf16x8 wb1 = *(const bf16x8*)(p + 32);
            float4 dv = *(const float4*)(dp + ct * 16);
            float4 uv = *(const float4*)(up + ct * 16);
            f32x4 o = {0.f, 0.f, 0.f, 0.f};
            // lane stores out[r0+g*16+m16][cb + ct*16 + quad*4 + i]
            o = __builtin_amdgcn_mfma_f32_16x16x32_bf16(wb0, ta0, o, 0, 0, 0);
            o = __builtin_amdgcn_mfma_f32_16x16x32_bf16(wb1, ta1, o, 0, 0, 0);
            f32x4 st;
            st[0] = o[0] + dv.x * uv.x;
            st[1] = o[1] + dv.y * uv.y;
            st[2] = o[2] + dv.z * uv.z;
            st[3] = o[3] + dv.w * uv.w;
            __builtin_nontemporal_store(st, (f32x4*)(op + ct * 16));
        }
        // no third barrier: tsh is double-buffered; red rewritten only after
        // the next group's phase-1, which every wave reaches post-reduce.
    }
}

extern "C" void kernel_launch(void* const* d_in, const int* in_sizes, int n_in,
                              void* d_out, int out_size, void* d_ws, size_t ws_size,
                              hipStream_t stream) {
    (void)in_sizes; (void)n_in; (void)out_size; (void)ws_size;
    const float* u   = (const float*)d_in[0];
    const float* Af  = (const float*)d_in[1];
    const float* Wbr = (const float*)d_in[2];
    const float* Wbs = (const float*)d_in[3];
    const float* Wcr = (const float*)d_in[4];
    const float* Wcm = (const float*)d_in[5];
    const float* Dv  = (const float*)d_in[6];
    float* out = (float*)d_out;

    char* ws = (char*)d_ws;
    float*    Mmid  = (float*)(ws + 0);            // 64*64*4    =   16384
    ushort_t* WeffT = (ushort_t*)(ws + 16384);     // 64*2048*2  =  262144
    ushort_t* WcT   = (ushort_t*)(ws + 278528);    // 2048*64*2  =  262144

    k_p1<<<16, 256, 0, stream>>>(Wbs, Af, Wcr, Mmid);
    k_p2<<<64, 256, 0, stream>>>(Wbr, Mmid, Wcm, WeffT, WcT);
    k_main<<<256, 512, 0, stream>>>(u, WeffT, WcT, Dv, out);
}